// Round 1
// baseline (633.987 us; speedup 1.0000x reference)
//
#include <hip/hip_runtime.h>

#define IN_DIM 128
#define HID    64
#define OUTD   64

// ---------------------------------------------------------------------------
// K1: per-node projection.  h0 = gelu(x @ w_in + b_in, exact); z = h0 @ w;
//     s1 = z . a[:64]; s2 = z . a[64:]
// wave-per-node, lane = output dim. Weights staged in LDS.
// ---------------------------------------------------------------------------
__global__ __launch_bounds__(256) void gat_node_proj(
    const float* __restrict__ x, const float* __restrict__ w_in,
    const float* __restrict__ b_in, const float* __restrict__ w,
    const float* __restrict__ a,
    float* __restrict__ z, float* __restrict__ s1, float* __restrict__ s2,
    int n_nodes)
{
    __shared__ float lwin[IN_DIM * HID];   // 32 KB
    __shared__ float lw[HID * OUTD];       // 16 KB
    __shared__ float la[2 * OUTD];
    __shared__ float lb[HID];
    __shared__ float h0buf[4][HID];

    const int tid = threadIdx.x;
    for (int i = tid; i < IN_DIM * HID; i += 256) lwin[i] = w_in[i];
    for (int i = tid; i < HID * OUTD; i += 256) lw[i] = w[i];
    if (tid < 2 * OUTD) la[tid] = a[tid];
    if (tid < HID) lb[tid] = b_in[tid];
    __syncthreads();

    const int wv = tid >> 6, lane = tid & 63;

    for (int n0 = blockIdx.x * 4; n0 < n_nodes; n0 += gridDim.x * 4) {
        const int n = n0 + wv;
        float h0 = 0.0f;
        if (n < n_nodes) {
            const float4* xr = (const float4*)(x + (size_t)n * IN_DIM);
            float acc = 0.0f;
            #pragma unroll
            for (int k4 = 0; k4 < IN_DIM / 4; ++k4) {
                float4 xv = xr[k4];
                acc = fmaf(xv.x, lwin[(4 * k4 + 0) * HID + lane], acc);
                acc = fmaf(xv.y, lwin[(4 * k4 + 1) * HID + lane], acc);
                acc = fmaf(xv.z, lwin[(4 * k4 + 2) * HID + lane], acc);
                acc = fmaf(xv.w, lwin[(4 * k4 + 3) * HID + lane], acc);
            }
            acc += lb[lane];
            // exact GELU: x * 0.5 * (1 + erf(x/sqrt(2)))
            h0 = acc * 0.5f * (1.0f + erff(acc * 0.7071067811865476f));
        }
        h0buf[wv][lane] = h0;
        __syncthreads();
        if (n < n_nodes) {
            float zv = 0.0f;
            #pragma unroll
            for (int j = 0; j < HID; ++j)
                zv = fmaf(h0buf[wv][j], lw[j * OUTD + lane], zv);
            z[(size_t)n * OUTD + lane] = zv;
            float p1 = zv * la[lane];
            float p2 = zv * la[OUTD + lane];
            #pragma unroll
            for (int off = 32; off; off >>= 1) {
                p1 += __shfl_xor(p1, off, 64);
                p2 += __shfl_xor(p2, off, 64);
            }
            if (lane == 0) { s1[n] = p1; s2[n] = p2; }
        }
        __syncthreads();
    }
}

// ---------------------------------------------------------------------------
// K2: per-edge: e = leaky_relu(s1[src]+s2[dst]); ex = exp(e)
//     h[dst,:] += ex * z[src,:]   (atomic);  denom[dst] += ex
// wave-per-edge, lane = feature dim -> coalesced 256B row read.
// Segment-max is skipped: alpha is exactly invariant to it; |e| <~ 3.
// ---------------------------------------------------------------------------
__global__ __launch_bounds__(256) void gat_edge_agg(
    const int* __restrict__ src, const int* __restrict__ dst,
    const float* __restrict__ s1, const float* __restrict__ s2,
    const float* __restrict__ z,
    float* __restrict__ h, float* __restrict__ denom, int n_edges)
{
    const int lane = threadIdx.x & 63;
    const int gw = (blockIdx.x * blockDim.x + threadIdx.x) >> 6;
    const int nw = (gridDim.x * blockDim.x) >> 6;

    for (int e = gw; e < n_edges; e += nw) {
        const int s = src[e];
        const int d = dst[e];
        float esc = s1[s] + s2[d];
        esc = esc > 0.0f ? esc : 0.01f * esc;
        const float ex = __expf(esc);
        const float val = ex * z[(size_t)s * OUTD + lane];
        atomicAdd(&h[(size_t)d * OUTD + lane], val);
        if (lane == 0) atomicAdd(&denom[d], ex);
    }
}

// ---------------------------------------------------------------------------
// K3: h[n,:] /= max(denom[n], 1e-9)
// ---------------------------------------------------------------------------
__global__ __launch_bounds__(256) void gat_normalize(
    float* __restrict__ h, const float* __restrict__ denom, int total)
{
    const int i = blockIdx.x * blockDim.x + threadIdx.x;
    if (i < total) {
        const float dn = denom[i >> 6];  // i / OUTD
        h[i] = h[i] / fmaxf(dn, 1e-9f);
    }
}

extern "C" void kernel_launch(void* const* d_in, const int* in_sizes, int n_in,
                              void* d_out, int out_size, void* d_ws, size_t ws_size,
                              hipStream_t stream)
{
    const float* x    = (const float*)d_in[0];
    const float* w_in = (const float*)d_in[1];
    const float* b_in = (const float*)d_in[2];
    const float* w    = (const float*)d_in[3];
    const float* a    = (const float*)d_in[4];
    const int*   src  = (const int*)d_in[5];
    const int*   dst  = (const int*)d_in[6];
    const int n_nodes = in_sizes[0] / IN_DIM;
    const int n_edges = in_sizes[5];

    float* h  = (float*)d_out;
    float* z  = (float*)d_ws;                     // n_nodes * 64
    float* s1 = z + (size_t)n_nodes * OUTD;       // n_nodes
    float* s2 = s1 + n_nodes;                     // n_nodes
    float* dn = s2 + n_nodes;                     // n_nodes

    hipMemsetAsync(d_out, 0, (size_t)out_size * sizeof(float), stream);
    hipMemsetAsync(dn, 0, (size_t)n_nodes * sizeof(float), stream);

    gat_node_proj<<<2048, 256, 0, stream>>>(x, w_in, b_in, w, a, z, s1, s2, n_nodes);
    gat_edge_agg<<<8192, 256, 0, stream>>>(src, dst, s1, s2, z, h, dn, n_edges);
    const int total = n_nodes * OUTD;
    gat_normalize<<<(total + 255) / 256, 256, 0, stream>>>(h, dn, total);
}

// Round 2
// 467.750 us; speedup vs baseline: 1.3554x; 1.3554x over previous
//
#include <hip/hip_runtime.h>

#define IN_DIM 128
#define HID    64
#define OUTD   64

__device__ __forceinline__ float gelu_exact(float v) {
    return v * 0.5f * (1.0f + erff(v * 0.70710678118654752f));
}

#define WREDUCE(v) { v += __shfl_xor(v,32,64); v += __shfl_xor(v,16,64); \
                     v += __shfl_xor(v,8,64);  v += __shfl_xor(v,4,64);  \
                     v += __shfl_xor(v,2,64);  v += __shfl_xor(v,1,64); }

// ---------------------------------------------------------------------------
// K1: node projection. 4 nodes per wave per iteration; weight ds_read shared
// across the 4 nodes; x rows scalarized (readfirstlane) -> s_load.
// ---------------------------------------------------------------------------
__global__ __launch_bounds__(256) void gat_node_proj(
    const float* __restrict__ x, const float* __restrict__ w_in,
    const float* __restrict__ b_in, const float* __restrict__ w,
    const float* __restrict__ a,
    float* __restrict__ z, float* __restrict__ s1, float* __restrict__ s2,
    int n_nodes)
{
    __shared__ float lwin[IN_DIM * HID];   // [k][h] 32 KB
    __shared__ float lw2[HID * OUTD];      // [j][o] 16 KB
    __shared__ float la[2 * OUTD];
    __shared__ float lb[HID];
    __shared__ float h0buf[4][4][HID];     // [wave][sub-node][h]

    const int tid = threadIdx.x;
    for (int i = tid; i < IN_DIM * HID; i += 256) lwin[i] = w_in[i];
    for (int i = tid; i < HID * OUTD; i += 256) lw2[i] = w[i];
    if (tid < 2 * OUTD) la[tid] = a[tid];
    if (tid < HID) lb[tid] = b_in[tid];
    __syncthreads();

    const int wv = tid >> 6, lane = tid & 63;
    const int gw = blockIdx.x * 4 + wv;
    const int nw = gridDim.x * 4;

    for (long long it = gw; it * 4 < n_nodes; it += nw) {
        const int base = __builtin_amdgcn_readfirstlane((int)(it * 4));
        const int nv = min(4, n_nodes - base);
        const float* xp = x + (size_t)base * IN_DIM;

        float h0v0, h0v1, h0v2, h0v3;
        if (nv == 4) {
            float a0 = 0.f, a1 = 0.f, a2 = 0.f, a3 = 0.f;
            #pragma unroll 8
            for (int k4 = 0; k4 < IN_DIM / 4; ++k4) {
                const float4 xa = *(const float4*)(xp + 0 * IN_DIM + 4 * k4);
                const float4 xb = *(const float4*)(xp + 1 * IN_DIM + 4 * k4);
                const float4 xc = *(const float4*)(xp + 2 * IN_DIM + 4 * k4);
                const float4 xd = *(const float4*)(xp + 3 * IN_DIM + 4 * k4);
                const float w0 = lwin[(4 * k4 + 0) * HID + lane];
                const float w1 = lwin[(4 * k4 + 1) * HID + lane];
                const float w2 = lwin[(4 * k4 + 2) * HID + lane];
                const float w3 = lwin[(4 * k4 + 3) * HID + lane];
                a0 = fmaf(xa.x, w0, a0); a0 = fmaf(xa.y, w1, a0);
                a0 = fmaf(xa.z, w2, a0); a0 = fmaf(xa.w, w3, a0);
                a1 = fmaf(xb.x, w0, a1); a1 = fmaf(xb.y, w1, a1);
                a1 = fmaf(xb.z, w2, a1); a1 = fmaf(xb.w, w3, a1);
                a2 = fmaf(xc.x, w0, a2); a2 = fmaf(xc.y, w1, a2);
                a2 = fmaf(xc.z, w2, a2); a2 = fmaf(xc.w, w3, a2);
                a3 = fmaf(xd.x, w0, a3); a3 = fmaf(xd.y, w1, a3);
                a3 = fmaf(xd.z, w2, a3); a3 = fmaf(xd.w, w3, a3);
            }
            const float b = lb[lane];
            h0v0 = gelu_exact(a0 + b); h0v1 = gelu_exact(a1 + b);
            h0v2 = gelu_exact(a2 + b); h0v3 = gelu_exact(a3 + b);
        } else {
            float t[4] = {0.f, 0.f, 0.f, 0.f};
            for (int i = 0; i < nv; ++i) {
                const float* xr = xp + (size_t)i * IN_DIM;
                float acc = 0.f;
                for (int k4 = 0; k4 < IN_DIM / 4; ++k4) {
                    float4 xv = *(const float4*)(xr + 4 * k4);
                    acc = fmaf(xv.x, lwin[(4 * k4 + 0) * HID + lane], acc);
                    acc = fmaf(xv.y, lwin[(4 * k4 + 1) * HID + lane], acc);
                    acc = fmaf(xv.z, lwin[(4 * k4 + 2) * HID + lane], acc);
                    acc = fmaf(xv.w, lwin[(4 * k4 + 3) * HID + lane], acc);
                }
                t[i] = gelu_exact(acc + lb[lane]);
            }
            h0v0 = t[0]; h0v1 = t[1]; h0v2 = t[2]; h0v3 = t[3];
        }

        // wave-private LDS exchange; in-order per-wave LDS pipe, no barrier
        h0buf[wv][0][lane] = h0v0;
        h0buf[wv][1][lane] = h0v1;
        h0buf[wv][2][lane] = h0v2;
        h0buf[wv][3][lane] = h0v3;

        float z0 = 0.f, z1 = 0.f, z2 = 0.f, z3 = 0.f;
        #pragma unroll 4
        for (int j = 0; j < HID; ++j) {
            const float wj = lw2[j * OUTD + lane];
            z0 = fmaf(h0buf[wv][0][j], wj, z0);
            z1 = fmaf(h0buf[wv][1][j], wj, z1);
            z2 = fmaf(h0buf[wv][2][j], wj, z2);
            z3 = fmaf(h0buf[wv][3][j], wj, z3);
        }

        const float a1c = la[lane], a2c = la[OUTD + lane];
        float p10 = z0 * a1c, p20 = z0 * a2c;
        float p11 = z1 * a1c, p21 = z1 * a2c;
        float p12 = z2 * a1c, p22 = z2 * a2c;
        float p13 = z3 * a1c, p23 = z3 * a2c;
        WREDUCE(p10); WREDUCE(p20); WREDUCE(p11); WREDUCE(p21);
        WREDUCE(p12); WREDUCE(p22); WREDUCE(p13); WREDUCE(p23);

        if (nv == 4) {
            z[(size_t)(base + 0) * OUTD + lane] = z0;
            z[(size_t)(base + 1) * OUTD + lane] = z1;
            z[(size_t)(base + 2) * OUTD + lane] = z2;
            z[(size_t)(base + 3) * OUTD + lane] = z3;
            if (lane == 0) {
                s1[base + 0] = p10; s2[base + 0] = p20;
                s1[base + 1] = p11; s2[base + 1] = p21;
                s1[base + 2] = p12; s2[base + 2] = p22;
                s1[base + 3] = p13; s2[base + 3] = p23;
            }
        } else {
            if (nv > 0) { z[(size_t)(base + 0) * OUTD + lane] = z0;
                if (lane == 0) { s1[base + 0] = p10; s2[base + 0] = p20; } }
            if (nv > 1) { z[(size_t)(base + 1) * OUTD + lane] = z1;
                if (lane == 0) { s1[base + 1] = p11; s2[base + 1] = p21; } }
            if (nv > 2) { z[(size_t)(base + 2) * OUTD + lane] = z2;
                if (lane == 0) { s1[base + 2] = p12; s2[base + 2] = p22; } }
        }
    }
}

// ---------------------------------------------------------------------------
// CSR build: histogram -> block scan -> block-sum scan -> add offsets -> scatter
// ---------------------------------------------------------------------------
__global__ __launch_bounds__(256) void k_hist(
    const int* __restrict__ dst, int* __restrict__ deg, int n_edges)
{
    for (int e = blockIdx.x * blockDim.x + threadIdx.x; e < n_edges;
         e += gridDim.x * blockDim.x)
        atomicAdd(&deg[dst[e]], 1);
}

__global__ __launch_bounds__(1024) void k_scan_block(
    const int* __restrict__ deg, int* __restrict__ rs,
    int* __restrict__ bsum, int n)
{
    __shared__ int buf[1024];
    const int tid = threadIdx.x;
    const int gid = blockIdx.x * 1024 + tid;
    const int v = (gid < n) ? deg[gid] : 0;
    buf[tid] = v;
    __syncthreads();
    #pragma unroll
    for (int off = 1; off < 1024; off <<= 1) {
        int t = (tid >= off) ? buf[tid - off] : 0;
        __syncthreads();
        buf[tid] += t;
        __syncthreads();
    }
    if (gid < n) rs[gid] = buf[tid] - v;   // exclusive, block-local
    if (tid == 1023) bsum[blockIdx.x] = buf[1023];
}

__global__ __launch_bounds__(128) void k_scan_bsum(int* __restrict__ bsum, int nb)
{
    __shared__ int buf[128];
    const int tid = threadIdx.x;
    const int v = (tid < nb) ? bsum[tid] : 0;
    buf[tid] = v;
    __syncthreads();
    #pragma unroll
    for (int off = 1; off < 128; off <<= 1) {
        int t = (tid >= off) ? buf[tid - off] : 0;
        __syncthreads();
        buf[tid] += t;
        __syncthreads();
    }
    if (tid < nb) bsum[tid] = buf[tid] - v;  // exclusive
}

__global__ __launch_bounds__(1024) void k_add_off(
    int* __restrict__ rs, int* __restrict__ cursor,
    const int* __restrict__ bsum, int n)
{
    const int gid = blockIdx.x * 1024 + threadIdx.x;
    if (gid < n) {
        const int v = rs[gid] + bsum[blockIdx.x];
        rs[gid] = v;
        cursor[gid] = v;
    }
}

__global__ __launch_bounds__(256) void k_scatter(
    const int* __restrict__ src, const int* __restrict__ dst,
    int* __restrict__ cursor, int* __restrict__ csr, int n_edges)
{
    for (int e = blockIdx.x * blockDim.x + threadIdx.x; e < n_edges;
         e += gridDim.x * blockDim.x) {
        const int pos = atomicAdd(&cursor[dst[e]], 1);
        csr[pos] = src[e];
    }
}

// ---------------------------------------------------------------------------
// K_agg: wave per dst node. Lane-parallel csr/s1 gather + exp; shfl-broadcast
// edges into coalesced z-row FMAs. No atomics; normalize fused.
// ---------------------------------------------------------------------------
__global__ __launch_bounds__(256) void gat_agg(
    const int* __restrict__ rs, const int* __restrict__ deg,
    const int* __restrict__ csr,
    const float* __restrict__ s1, const float* __restrict__ s2,
    const float* __restrict__ z, float* __restrict__ h, int n_nodes)
{
    const int wv = threadIdx.x >> 6, lane = threadIdx.x & 63;
    const int node = blockIdx.x * 4 + wv;
    if (node >= n_nodes) return;

    const int base = rs[node];
    const int cnt = deg[node];
    const float s2d = s2[node];

    float acc = 0.f, den = 0.f;
    for (int c0 = 0; c0 < cnt; c0 += 64) {
        const int m = min(64, cnt - c0);
        int sidx = 0;
        float exv = 0.f;
        if (lane < m) {
            sidx = csr[base + c0 + lane];
            float e = s1[sidx] + s2d;
            e = e > 0.f ? e : 0.01f * e;
            exv = __expf(e);
        }
        float dsum = exv;
        WREDUCE(dsum);
        den += dsum;
        for (int j = 0; j < m; ++j) {
            const int s   = __shfl(sidx, j, 64);
            const float ex = __shfl(exv, j, 64);
            acc = fmaf(ex, z[(size_t)s * OUTD + lane], acc);
        }
    }
    h[(size_t)node * OUTD + lane] = acc / fmaxf(den, 1e-9f);
}

extern "C" void kernel_launch(void* const* d_in, const int* in_sizes, int n_in,
                              void* d_out, int out_size, void* d_ws, size_t ws_size,
                              hipStream_t stream)
{
    const float* x    = (const float*)d_in[0];
    const float* w_in = (const float*)d_in[1];
    const float* b_in = (const float*)d_in[2];
    const float* w    = (const float*)d_in[3];
    const float* a    = (const float*)d_in[4];
    const int*   src  = (const int*)d_in[5];
    const int*   dst  = (const int*)d_in[6];
    const int n_nodes = in_sizes[0] / IN_DIM;
    const int n_edges = in_sizes[5];

    float* h = (float*)d_out;

    // workspace layout
    float* z      = (float*)d_ws;                       // n_nodes*64
    float* s1     = z + (size_t)n_nodes * OUTD;         // n_nodes
    float* s2     = s1 + n_nodes;                       // n_nodes
    int*   deg    = (int*)(s2 + n_nodes);               // n_nodes
    int*   rs     = deg + n_nodes;                      // n_nodes
    int*   cursor = rs + n_nodes;                       // n_nodes
    int*   bsum   = cursor + n_nodes;                   // 128
    int*   csr    = bsum + 128;                         // n_edges

    const int nb = (n_nodes + 1023) / 1024;

    hipMemsetAsync(deg, 0, (size_t)n_nodes * sizeof(int), stream);

    k_hist<<<2048, 256, 0, stream>>>(dst, deg, n_edges);
    k_scan_block<<<nb, 1024, 0, stream>>>(deg, rs, bsum, n_nodes);
    k_scan_bsum<<<1, 128, 0, stream>>>(bsum, nb);
    k_add_off<<<nb, 1024, 0, stream>>>(rs, cursor, bsum, n_nodes);
    k_scatter<<<2048, 256, 0, stream>>>(src, dst, cursor, csr, n_edges);

    gat_node_proj<<<6250, 256, 0, stream>>>(x, w_in, b_in, w, a, z, s1, s2, n_nodes);

    gat_agg<<<(n_nodes + 3) / 4, 256, 0, stream>>>(rs, deg, csr, s1, s2, z, h, n_nodes);
}

// Round 3
// 347.601 us; speedup vs baseline: 1.8239x; 1.3457x over previous
//
#include <hip/hip_runtime.h>
#include <hip/hip_bf16.h>

#define IN_DIM 128
#define HID    64
#define OUTD   64

typedef __attribute__((ext_vector_type(8))) short bf16x8;
typedef __attribute__((ext_vector_type(4))) float f32x4;

__device__ __forceinline__ float gelu_exact(float v) {
    return v * 0.5f * (1.0f + erff(v * 0.70710678118654752f));
}
__device__ __forceinline__ short f2bf(float f) {
    __hip_bfloat16 b = __float2bfloat16(f);   // RNE
    return *reinterpret_cast<short*>(&b);
}
__device__ __forceinline__ float bf2f(ushort u) {
    return __uint_as_float(((unsigned)u) << 16);
}

#define WREDUCE(v) { v += __shfl_xor(v,32,64); v += __shfl_xor(v,16,64); \
                     v += __shfl_xor(v,8,64);  v += __shfl_xor(v,4,64);  \
                     v += __shfl_xor(v,2,64);  v += __shfl_xor(v,1,64); }

// ---------------------------------------------------------------------------
// K1: node projection via MFMA bf16. Block = 4 waves, 64 nodes/tile
// (16 nodes/wave). Weights held as B-fragments in VGPRs. h0 crosses the
// C-layout -> A-layout boundary via a wave-private XOR-swizzled LDS tile.
//   GEMM1: h0[16x64] = x[16x128] @ w_in[128x64]  (4 N-tiles x 4 K-steps)
//   GEMM2: z [16x64] = h0[16x64] @ w   [64x64]   (4 N-tiles x 2 K-steps)
// MFMA 16x16x32 layouts (m89-verified family):
//   A: lane l holds A[l&15][8*(l>>4)+e]  e=0..7
//   B: lane l holds B[8*(l>>4)+e][l&15]
//   C: lane l holds C[4*(l>>4)+r][l&15]  r=0..3
// ---------------------------------------------------------------------------
__global__ __launch_bounds__(256) void gat_node_proj_mfma(
    const float* __restrict__ x, const float* __restrict__ w_in,
    const float* __restrict__ b_in, const float* __restrict__ w,
    const float* __restrict__ a,
    ushort* __restrict__ zb, float* __restrict__ s1, float* __restrict__ s2,
    int n_nodes, int ntiles)
{
    __shared__ ushort h0s[4][16 * 64];   // 2 KB per wave

    const int tid = threadIdx.x;
    const int wv = tid >> 6, l = tid & 63;
    const int c = l & 15, g = l >> 4;

    // ---- preload weights into register fragments (bf16) ----
    bf16x8 B1[4][4];                     // [k-step][n-tile]
    #pragma unroll
    for (int s = 0; s < 4; ++s)
        #pragma unroll
        for (int t = 0; t < 4; ++t) {
            bf16x8 f;
            #pragma unroll
            for (int e = 0; e < 8; ++e)
                f[e] = f2bf(w_in[(s * 32 + g * 8 + e) * HID + t * 16 + c]);
            B1[s][t] = f;
        }
    bf16x8 B2[2][4];
    #pragma unroll
    for (int s = 0; s < 2; ++s)
        #pragma unroll
        for (int t = 0; t < 4; ++t) {
            bf16x8 f;
            #pragma unroll
            for (int e = 0; e < 8; ++e)
                f[e] = f2bf(w[(s * 32 + g * 8 + e) * OUTD + t * 16 + c]);
            B2[s][t] = f;
        }
    float bias[4], a1c[4], a2c[4];
    #pragma unroll
    for (int t = 0; t < 4; ++t) {
        bias[t] = b_in[t * 16 + c];
        a1c[t]  = a[t * 16 + c];
        a2c[t]  = a[OUTD + t * 16 + c];
    }

    ushort* hrow = &h0s[wv][0];

    for (int tile = blockIdx.x; tile < ntiles; tile += gridDim.x) {
        const int nbase = tile * 64 + wv * 16;

        // ---- A-fragments for GEMM1 from global x (fp32 -> bf16) ----
        const int row = min(nbase + c, n_nodes - 1);
        const float* xp = x + (size_t)row * IN_DIM;
        bf16x8 A1[4];
        #pragma unroll
        for (int s = 0; s < 4; ++s) {
            const float4 u0 = *(const float4*)(xp + s * 32 + g * 8);
            const float4 u1 = *(const float4*)(xp + s * 32 + g * 8 + 4);
            bf16x8 f;
            f[0] = f2bf(u0.x); f[1] = f2bf(u0.y); f[2] = f2bf(u0.z); f[3] = f2bf(u0.w);
            f[4] = f2bf(u1.x); f[5] = f2bf(u1.y); f[6] = f2bf(u1.z); f[7] = f2bf(u1.w);
            A1[s] = f;
        }

        // ---- GEMM1 + bias + exact GELU -> swizzled LDS (bf16) ----
        #pragma unroll
        for (int t = 0; t < 4; ++t) {
            f32x4 acc = {0.f, 0.f, 0.f, 0.f};
            #pragma unroll
            for (int s = 0; s < 4; ++s)
                acc = __builtin_amdgcn_mfma_f32_16x16x32_bf16(A1[s], B1[s][t], acc, 0, 0, 0);
            #pragma unroll
            for (int r = 0; r < 4; ++r) {
                const int m = g * 4 + r;                 // node-in-tile
                const int n = t * 16 + c;                // hid dim
                const float h0 = gelu_exact(acc[r] + bias[t]);
                // ushort-index swizzle: idx = n ^ ((m&7)<<3)  (16B-chunk XOR)
                hrow[m * 64 + (n ^ ((m & 7) << 3))] = (ushort)f2bf(h0);
            }
        }
        __syncthreads();   // cross-lane LDS visibility (uniform trip count)

        // ---- A-fragments for GEMM2 from swizzled LDS ----
        bf16x8 A2[2];
        #pragma unroll
        for (int s = 0; s < 2; ++s) {
            const int k = s * 32 + g * 8;                // hid dim, 8-contig
            A2[s] = *(const bf16x8*)(hrow + c * 64 + (k ^ ((c & 7) << 3)));
        }

        // ---- GEMM2 ----
        f32x4 C2[4];
        #pragma unroll
        for (int t = 0; t < 4; ++t) {
            f32x4 acc = {0.f, 0.f, 0.f, 0.f};
            acc = __builtin_amdgcn_mfma_f32_16x16x32_bf16(A2[0], B2[0][t], acc, 0, 0, 0);
            acc = __builtin_amdgcn_mfma_f32_16x16x32_bf16(A2[1], B2[1][t], acc, 0, 0, 0);
            C2[t] = acc;
        }

        // ---- z stores (bf16) + s1/s2 partials ----
        float p1v[4] = {0.f, 0.f, 0.f, 0.f}, p2v[4] = {0.f, 0.f, 0.f, 0.f};
        #pragma unroll
        for (int t = 0; t < 4; ++t)
            #pragma unroll
            for (int r = 0; r < 4; ++r) {
                p1v[r] = fmaf(C2[t][r], a1c[t], p1v[r]);
                p2v[r] = fmaf(C2[t][r], a2c[t], p2v[r]);
                const int node = nbase + g * 4 + r;
                if (node < n_nodes)
                    zb[(size_t)node * OUTD + t * 16 + c] = (ushort)f2bf(C2[t][r]);
            }

        // reduce over the 16 lanes of each row-group (cols) -> s1/s2
        #pragma unroll
        for (int r = 0; r < 4; ++r) {
            p1v[r] += __shfl_xor(p1v[r], 1, 64);
            p1v[r] += __shfl_xor(p1v[r], 2, 64);
            p1v[r] += __shfl_xor(p1v[r], 4, 64);
            p1v[r] += __shfl_xor(p1v[r], 8, 64);
            p2v[r] += __shfl_xor(p2v[r], 1, 64);
            p2v[r] += __shfl_xor(p2v[r], 2, 64);
            p2v[r] += __shfl_xor(p2v[r], 4, 64);
            p2v[r] += __shfl_xor(p2v[r], 8, 64);
        }
        const float v1 = (c == 0) ? p1v[0] : (c == 1) ? p1v[1] : (c == 2) ? p1v[2] : p1v[3];
        const float v2 = (c == 0) ? p2v[0] : (c == 1) ? p2v[1] : (c == 2) ? p2v[2] : p2v[3];
        const int snode = nbase + g * 4 + c;
        if (c < 4 && snode < n_nodes) { s1[snode] = v1; s2[snode] = v2; }
        __syncthreads();   // protect h0s before next tile's writes
    }
}

// ---------------------------------------------------------------------------
// CSR build: histogram -> block scan -> block-sum scan -> add offsets -> scatter
// ---------------------------------------------------------------------------
__global__ __launch_bounds__(256) void k_hist(
    const int* __restrict__ dst, int* __restrict__ deg, int n_edges)
{
    for (int e = blockIdx.x * blockDim.x + threadIdx.x; e < n_edges;
         e += gridDim.x * blockDim.x)
        atomicAdd(&deg[dst[e]], 1);
}

__global__ __launch_bounds__(1024) void k_scan_block(
    const int* __restrict__ deg, int* __restrict__ rs,
    int* __restrict__ bsum, int n)
{
    __shared__ int buf[1024];
    const int tid = threadIdx.x;
    const int gid = blockIdx.x * 1024 + tid;
    const int v = (gid < n) ? deg[gid] : 0;
    buf[tid] = v;
    __syncthreads();
    #pragma unroll
    for (int off = 1; off < 1024; off <<= 1) {
        int t = (tid >= off) ? buf[tid - off] : 0;
        __syncthreads();
        buf[tid] += t;
        __syncthreads();
    }
    if (gid < n) rs[gid] = buf[tid] - v;
    if (tid == 1023) bsum[blockIdx.x] = buf[1023];
}

__global__ __launch_bounds__(128) void k_scan_bsum(int* __restrict__ bsum, int nb)
{
    __shared__ int buf[128];
    const int tid = threadIdx.x;
    const int v = (tid < nb) ? bsum[tid] : 0;
    buf[tid] = v;
    __syncthreads();
    #pragma unroll
    for (int off = 1; off < 128; off <<= 1) {
        int t = (tid >= off) ? buf[tid - off] : 0;
        __syncthreads();
        buf[tid] += t;
        __syncthreads();
    }
    if (tid < nb) bsum[tid] = buf[tid] - v;
}

__global__ __launch_bounds__(1024) void k_add_off(
    int* __restrict__ rs, int* __restrict__ cursor,
    const int* __restrict__ bsum, int n)
{
    const int gid = blockIdx.x * 1024 + threadIdx.x;
    if (gid < n) {
        const int v = rs[gid] + bsum[blockIdx.x];
        rs[gid] = v;
        cursor[gid] = v;
    }
}

__global__ __launch_bounds__(256) void k_scatter(
    const int* __restrict__ src, const int* __restrict__ dst,
    int* __restrict__ cursor, int* __restrict__ csr, int n_edges)
{
    for (int e = blockIdx.x * blockDim.x + threadIdx.x; e < n_edges;
         e += gridDim.x * blockDim.x) {
        const int pos = atomicAdd(&cursor[dst[e]], 1);
        csr[pos] = src[e];
    }
}

// ---------------------------------------------------------------------------
// K_agg: wave per dst node; bf16 z gather (halved bytes); normalize fused.
// ---------------------------------------------------------------------------
__global__ __launch_bounds__(256) void gat_agg(
    const int* __restrict__ rs, const int* __restrict__ deg,
    const int* __restrict__ csr,
    const float* __restrict__ s1, const float* __restrict__ s2,
    const ushort* __restrict__ zb, float* __restrict__ h, int n_nodes)
{
    const int wv = threadIdx.x >> 6, lane = threadIdx.x & 63;
    const int node = blockIdx.x * 4 + wv;
    if (node >= n_nodes) return;

    const int base = rs[node];
    const int cnt = deg[node];
    const float s2d = s2[node];

    float acc = 0.f, den = 0.f;
    for (int c0 = 0; c0 < cnt; c0 += 64) {
        const int m = min(64, cnt - c0);
        int sidx = 0;
        float exv = 0.f;
        if (lane < m) {
            sidx = csr[base + c0 + lane];
            float e = s1[sidx] + s2d;
            e = e > 0.f ? e : 0.01f * e;
            exv = __expf(e);
        }
        float dsum = exv;
        WREDUCE(dsum);
        den += dsum;
        for (int j = 0; j < m; ++j) {
            const int s    = __shfl(sidx, j, 64);
            const float ex = __shfl(exv, j, 64);
            acc = fmaf(ex, bf2f(zb[(size_t)s * OUTD + lane]), acc);
        }
    }
    h[(size_t)node * OUTD + lane] = acc / fmaxf(den, 1e-9f);
}

extern "C" void kernel_launch(void* const* d_in, const int* in_sizes, int n_in,
                              void* d_out, int out_size, void* d_ws, size_t ws_size,
                              hipStream_t stream)
{
    const float* x    = (const float*)d_in[0];
    const float* w_in = (const float*)d_in[1];
    const float* b_in = (const float*)d_in[2];
    const float* w    = (const float*)d_in[3];
    const float* a    = (const float*)d_in[4];
    const int*   src  = (const int*)d_in[5];
    const int*   dst  = (const int*)d_in[6];
    const int n_nodes = in_sizes[0] / IN_DIM;
    const int n_edges = in_sizes[5];

    float* h = (float*)d_out;

    // workspace layout
    ushort* zb    = (ushort*)d_ws;                      // n_nodes*64 bf16
    float*  s1    = (float*)(zb + (size_t)n_nodes * OUTD);
    float*  s2    = s1 + n_nodes;
    int*    deg   = (int*)(s2 + n_nodes);
    int*    rs    = deg + n_nodes;
    int*    cursor= rs + n_nodes;
    int*    bsum  = cursor + n_nodes;
    int*    csr   = bsum + 128;

    const int nb = (n_nodes + 1023) / 1024;
    const int ntiles = (n_nodes + 63) / 64;

    hipMemsetAsync(deg, 0, (size_t)n_nodes * sizeof(int), stream);

    k_hist<<<2048, 256, 0, stream>>>(dst, deg, n_edges);
    k_scan_block<<<nb, 1024, 0, stream>>>(deg, rs, bsum, n_nodes);
    k_scan_bsum<<<1, 128, 0, stream>>>(bsum, nb);
    k_add_off<<<nb, 1024, 0, stream>>>(rs, cursor, bsum, n_nodes);
    k_scatter<<<2048, 256, 0, stream>>>(src, dst, cursor, csr, n_edges);

    gat_node_proj_mfma<<<523, 256, 0, stream>>>(x, w_in, b_in, w, a,
                                                zb, s1, s2, n_nodes, ntiles);

    gat_agg<<<(n_nodes + 3) / 4, 256, 0, stream>>>(rs, deg, csr, s1, s2, zb, h, n_nodes);
}

// Round 4
// 285.450 us; speedup vs baseline: 2.2210x; 1.2177x over previous
//
#include <hip/hip_runtime.h>
#include <hip/hip_bf16.h>

#define IN_DIM 128
#define HID    64
#define OUTD   64
#define NPART  8

typedef __attribute__((ext_vector_type(8))) short bf16x8;
typedef __attribute__((ext_vector_type(4))) float f32x4;

__device__ __forceinline__ float gelu_exact(float v) {
    return v * 0.5f * (1.0f + erff(v * 0.70710678118654752f));
}
__device__ __forceinline__ short f2bf(float f) {
    __hip_bfloat16 b = __float2bfloat16(f);   // RNE
    return *reinterpret_cast<short*>(&b);
}
__device__ __forceinline__ float bf2f(ushort u) {
    return __uint_as_float(((unsigned)u) << 16);
}

#define WREDUCE(v) { v += __shfl_xor(v,32,64); v += __shfl_xor(v,16,64); \
                     v += __shfl_xor(v,8,64);  v += __shfl_xor(v,4,64);  \
                     v += __shfl_xor(v,2,64);  v += __shfl_xor(v,1,64); }

// ---------------------------------------------------------------------------
// K1: node projection via MFMA bf16 (unchanged from R3; ~25 us, not the
// bottleneck). 16 nodes/wave, weights in VGPR B-fragments, h0 through
// XOR-swizzled wave-private LDS.
// ---------------------------------------------------------------------------
__global__ __launch_bounds__(256) void gat_node_proj_mfma(
    const float* __restrict__ x, const float* __restrict__ w_in,
    const float* __restrict__ b_in, const float* __restrict__ w,
    const float* __restrict__ a,
    ushort* __restrict__ zb, float* __restrict__ s1, float* __restrict__ s2,
    int n_nodes, int ntiles)
{
    __shared__ ushort h0s[4][16 * 64];

    const int tid = threadIdx.x;
    const int wv = tid >> 6, l = tid & 63;
    const int c = l & 15, g = l >> 4;

    bf16x8 B1[4][4];
    #pragma unroll
    for (int s = 0; s < 4; ++s)
        #pragma unroll
        for (int t = 0; t < 4; ++t) {
            bf16x8 f;
            #pragma unroll
            for (int e = 0; e < 8; ++e)
                f[e] = f2bf(w_in[(s * 32 + g * 8 + e) * HID + t * 16 + c]);
            B1[s][t] = f;
        }
    bf16x8 B2[2][4];
    #pragma unroll
    for (int s = 0; s < 2; ++s)
        #pragma unroll
        for (int t = 0; t < 4; ++t) {
            bf16x8 f;
            #pragma unroll
            for (int e = 0; e < 8; ++e)
                f[e] = f2bf(w[(s * 32 + g * 8 + e) * OUTD + t * 16 + c]);
            B2[s][t] = f;
        }
    float bias[4], a1c[4], a2c[4];
    #pragma unroll
    for (int t = 0; t < 4; ++t) {
        bias[t] = b_in[t * 16 + c];
        a1c[t]  = a[t * 16 + c];
        a2c[t]  = a[OUTD + t * 16 + c];
    }

    ushort* hrow = &h0s[wv][0];

    for (int tile = blockIdx.x; tile < ntiles; tile += gridDim.x) {
        const int nbase = tile * 64 + wv * 16;

        const int row = min(nbase + c, n_nodes - 1);
        const float* xp = x + (size_t)row * IN_DIM;
        bf16x8 A1[4];
        #pragma unroll
        for (int s = 0; s < 4; ++s) {
            const float4 u0 = *(const float4*)(xp + s * 32 + g * 8);
            const float4 u1 = *(const float4*)(xp + s * 32 + g * 8 + 4);
            bf16x8 f;
            f[0] = f2bf(u0.x); f[1] = f2bf(u0.y); f[2] = f2bf(u0.z); f[3] = f2bf(u0.w);
            f[4] = f2bf(u1.x); f[5] = f2bf(u1.y); f[6] = f2bf(u1.z); f[7] = f2bf(u1.w);
            A1[s] = f;
        }

        #pragma unroll
        for (int t = 0; t < 4; ++t) {
            f32x4 acc = {0.f, 0.f, 0.f, 0.f};
            #pragma unroll
            for (int s = 0; s < 4; ++s)
                acc = __builtin_amdgcn_mfma_f32_16x16x32_bf16(A1[s], B1[s][t], acc, 0, 0, 0);
            #pragma unroll
            for (int r = 0; r < 4; ++r) {
                const int m = g * 4 + r;
                const int n = t * 16 + c;
                const float h0 = gelu_exact(acc[r] + bias[t]);
                hrow[m * 64 + (n ^ ((m & 7) << 3))] = (ushort)f2bf(h0);
            }
        }
        __syncthreads();

        bf16x8 A2[2];
        #pragma unroll
        for (int s = 0; s < 2; ++s) {
            const int k = s * 32 + g * 8;
            A2[s] = *(const bf16x8*)(hrow + c * 64 + (k ^ ((c & 7) << 3)));
        }

        f32x4 C2[4];
        #pragma unroll
        for (int t = 0; t < 4; ++t) {
            f32x4 acc = {0.f, 0.f, 0.f, 0.f};
            acc = __builtin_amdgcn_mfma_f32_16x16x32_bf16(A2[0], B2[0][t], acc, 0, 0, 0);
            acc = __builtin_amdgcn_mfma_f32_16x16x32_bf16(A2[1], B2[1][t], acc, 0, 0, 0);
            C2[t] = acc;
        }

        float p1v[4] = {0.f, 0.f, 0.f, 0.f}, p2v[4] = {0.f, 0.f, 0.f, 0.f};
        #pragma unroll
        for (int t = 0; t < 4; ++t)
            #pragma unroll
            for (int r = 0; r < 4; ++r) {
                p1v[r] = fmaf(C2[t][r], a1c[t], p1v[r]);
                p2v[r] = fmaf(C2[t][r], a2c[t], p2v[r]);
                const int node = nbase + g * 4 + r;
                if (node < n_nodes)
                    zb[(size_t)node * OUTD + t * 16 + c] = (ushort)f2bf(C2[t][r]);
            }

        #pragma unroll
        for (int r = 0; r < 4; ++r) {
            p1v[r] += __shfl_xor(p1v[r], 1, 64);
            p1v[r] += __shfl_xor(p1v[r], 2, 64);
            p1v[r] += __shfl_xor(p1v[r], 4, 64);
            p1v[r] += __shfl_xor(p1v[r], 8, 64);
            p2v[r] += __shfl_xor(p2v[r], 1, 64);
            p2v[r] += __shfl_xor(p2v[r], 2, 64);
            p2v[r] += __shfl_xor(p2v[r], 4, 64);
            p2v[r] += __shfl_xor(p2v[r], 8, 64);
        }
        const float v1 = (c == 0) ? p1v[0] : (c == 1) ? p1v[1] : (c == 2) ? p1v[2] : p1v[3];
        const float v2 = (c == 0) ? p2v[0] : (c == 1) ? p2v[1] : (c == 2) ? p2v[2] : p2v[3];
        const int snode = nbase + g * 4 + c;
        if (c < 4 && snode < n_nodes) { s1[snode] = v1; s2[snode] = v2; }
        __syncthreads();
    }
}

// ---------------------------------------------------------------------------
// CSR build, dst-PARTITIONED: partition p = blockIdx % 8 handles dst in
// [p*PART,(p+1)*PART). blockIdx%8 round-robins to XCDs, so each csr/deg
// region's writers share one XCD L2 -> lines assembled fully before one
// writeback (kills the 17x write amplification seen in R3). Edge arrays are
// read 8x but are L3-resident after first touch.
// ---------------------------------------------------------------------------
__global__ __launch_bounds__(256) void k_hist_part(
    const int* __restrict__ dst, int* __restrict__ deg, int n_edges, int part_sz)
{
    const int p = blockIdx.x & (NPART - 1);
    const int lo = p * part_sz, hi = lo + part_sz;
    const int tp = (blockIdx.x >> 3) * blockDim.x + threadIdx.x;
    const int stride = (gridDim.x >> 3) * blockDim.x;
    for (int e = tp; e < n_edges; e += stride) {
        const int d = dst[e];
        if (d >= lo && d < hi) atomicAdd(&deg[d], 1);
    }
}

__global__ __launch_bounds__(1024) void k_scan_block(
    const int* __restrict__ deg, int* __restrict__ rs,
    int* __restrict__ bsum, int n)
{
    __shared__ int buf[1024];
    const int tid = threadIdx.x;
    const int gid = blockIdx.x * 1024 + tid;
    const int v = (gid < n) ? deg[gid] : 0;
    buf[tid] = v;
    __syncthreads();
    #pragma unroll
    for (int off = 1; off < 1024; off <<= 1) {
        int t = (tid >= off) ? buf[tid - off] : 0;
        __syncthreads();
        buf[tid] += t;
        __syncthreads();
    }
    if (gid < n) rs[gid] = buf[tid] - v;
    if (tid == 1023) bsum[blockIdx.x] = buf[1023];
}

__global__ __launch_bounds__(128) void k_scan_bsum(int* __restrict__ bsum, int nb)
{
    __shared__ int buf[128];
    const int tid = threadIdx.x;
    const int v = (tid < nb) ? bsum[tid] : 0;
    buf[tid] = v;
    __syncthreads();
    #pragma unroll
    for (int off = 1; off < 128; off <<= 1) {
        int t = (tid >= off) ? buf[tid - off] : 0;
        __syncthreads();
        buf[tid] += t;
        __syncthreads();
    }
    if (tid < nb) bsum[tid] = buf[tid] - v;
}

__global__ __launch_bounds__(1024) void k_add_off(
    int* __restrict__ rs, int* __restrict__ cursor,
    const int* __restrict__ bsum, int n)
{
    const int gid = blockIdx.x * 1024 + threadIdx.x;
    if (gid < n) {
        const int v = rs[gid] + bsum[blockIdx.x];
        rs[gid] = v;
        cursor[gid] = v;
    }
}

__global__ __launch_bounds__(256) void k_scatter_part(
    const int* __restrict__ src, const int* __restrict__ dst,
    int* __restrict__ cursor, int* __restrict__ csr, int n_edges, int part_sz)
{
    const int p = blockIdx.x & (NPART - 1);
    const int lo = p * part_sz, hi = lo + part_sz;
    const int tp = (blockIdx.x >> 3) * blockDim.x + threadIdx.x;
    const int stride = (gridDim.x >> 3) * blockDim.x;
    for (int e = tp; e < n_edges; e += stride) {
        const int d = dst[e];
        if (d >= lo && d < hi) {
            const int pos = atomicAdd(&cursor[d], 1);
            csr[pos] = src[e];
        }
    }
}

// ---------------------------------------------------------------------------
// K_agg: wave per dst node; bf16 z gather; normalize fused. (unchanged)
// ---------------------------------------------------------------------------
__global__ __launch_bounds__(256) void gat_agg(
    const int* __restrict__ rs, const int* __restrict__ deg,
    const int* __restrict__ csr,
    const float* __restrict__ s1, const float* __restrict__ s2,
    const ushort* __restrict__ zb, float* __restrict__ h, int n_nodes)
{
    const int wv = threadIdx.x >> 6, lane = threadIdx.x & 63;
    const int node = blockIdx.x * 4 + wv;
    if (node >= n_nodes) return;

    const int base = rs[node];
    const int cnt = deg[node];
    const float s2d = s2[node];

    float acc = 0.f, den = 0.f;
    for (int c0 = 0; c0 < cnt; c0 += 64) {
        const int m = min(64, cnt - c0);
        int sidx = 0;
        float exv = 0.f;
        if (lane < m) {
            sidx = csr[base + c0 + lane];
            float e = s1[sidx] + s2d;
            e = e > 0.f ? e : 0.01f * e;
            exv = __expf(e);
        }
        float dsum = exv;
        WREDUCE(dsum);
        den += dsum;
        for (int j = 0; j < m; ++j) {
            const int s    = __shfl(sidx, j, 64);
            const float ex = __shfl(exv, j, 64);
            acc = fmaf(ex, bf2f(zb[(size_t)s * OUTD + lane]), acc);
        }
    }
    h[(size_t)node * OUTD + lane] = acc / fmaxf(den, 1e-9f);
}

extern "C" void kernel_launch(void* const* d_in, const int* in_sizes, int n_in,
                              void* d_out, int out_size, void* d_ws, size_t ws_size,
                              hipStream_t stream)
{
    const float* x    = (const float*)d_in[0];
    const float* w_in = (const float*)d_in[1];
    const float* b_in = (const float*)d_in[2];
    const float* w    = (const float*)d_in[3];
    const float* a    = (const float*)d_in[4];
    const int*   src  = (const int*)d_in[5];
    const int*   dst  = (const int*)d_in[6];
    const int n_nodes = in_sizes[0] / IN_DIM;
    const int n_edges = in_sizes[5];

    float* h = (float*)d_out;

    ushort* zb    = (ushort*)d_ws;                      // n_nodes*64 bf16
    float*  s1    = (float*)(zb + (size_t)n_nodes * OUTD);
    float*  s2    = s1 + n_nodes;
    int*    deg   = (int*)(s2 + n_nodes);
    int*    rs    = deg + n_nodes;
    int*    cursor= rs + n_nodes;
    int*    bsum  = cursor + n_nodes;
    int*    csr   = bsum + 128;

    const int nb = (n_nodes + 1023) / 1024;
    const int ntiles = (n_nodes + 63) / 64;
    const int part_sz = (n_nodes + NPART - 1) / NPART;

    hipMemsetAsync(deg, 0, (size_t)n_nodes * sizeof(int), stream);

    k_hist_part<<<2048, 256, 0, stream>>>(dst, deg, n_edges, part_sz);
    k_scan_block<<<nb, 1024, 0, stream>>>(deg, rs, bsum, n_nodes);
    k_scan_bsum<<<1, 128, 0, stream>>>(bsum, nb);
    k_add_off<<<nb, 1024, 0, stream>>>(rs, cursor, bsum, n_nodes);
    k_scatter_part<<<2048, 256, 0, stream>>>(src, dst, cursor, csr, n_edges, part_sz);

    gat_node_proj_mfma<<<523, 256, 0, stream>>>(x, w_in, b_in, w, a,
                                                zb, s1, s2, n_nodes, ntiles);

    gat_agg<<<(n_nodes + 3) / 4, 256, 0, stream>>>(rs, deg, csr, s1, s2, zb, h, n_nodes);
}